// Round 12
// baseline (669.146 us; speedup 1.0000x reference)
//
#include <hip/hip_runtime.h>

// MultiHeadedAttention: out = ((softmax(softmax(QK^T/8)+softmax(mask/128)))V) @ Wo
// Q,K,V (128,512,768) fp32 -> flat [65536][768]. Attention slice (l,h) = rows
// l*128..+127, cols h*64..+63 of the flat projection buffers.
// R11 post-mortem: deleting the post-QK^T barrier gained ~3us even at 3
// blocks/CU (49KB) -> phase-lock was real; keep the deletion. This round
// (single variable): shrink ps to a QUARTER-column buffer (8KB) -> LDS 40KB ->
// 4 blocks/CU restored (threads now the binding cap). P is consumed as 4
// independent k-slices (one 16x16x32 MFMA each), so PV runs 4 write/read/MFMA
// quarters through the wave-local 8KB buffer with lgkm fences only (no block
// barrier). ps swizzle re-derived for the 64B row stride: gi ^= (q&3)<<1 —
// even XOR keeps b128 read pairs contiguous (read beat 2-way = free; write
// beat 4-way on small b64 writes, acceptable). vt/ks/QK^T/softmax untouched.
//   convb: fp32->bf16 L3-staging. gemm8: R1 cross-phase ds_read prefetch,
//   vmcnt 6/4/0 (session-plateaued at 36% MfmaUtil after 5 failed probes).

typedef __attribute__((ext_vector_type(8))) __bf16 bf16x8;
typedef __attribute__((ext_vector_type(4))) __bf16 bf16x4;
typedef __attribute__((ext_vector_type(4))) float f32x4;

#define DM 768
#define LOG2E 1.44269504f

__device__ __forceinline__ unsigned short f2bf(float x) {
  unsigned u = __float_as_uint(x);
  u += 0x7FFFu + ((u >> 16) & 1u);   // RNE
  return (unsigned short)(u >> 16);
}

__device__ __forceinline__ void gl_lds16(const void* g, void* l) {
  __builtin_amdgcn_global_load_lds(
      (const __attribute__((address_space(1))) unsigned int*)g,
      (__attribute__((address_space(3))) unsigned int*)l, 16, 0, 0);
}

// ---------------- prep: transpose+convert 4 weights to bf16 [op][n][k] ----------------
__global__ __launch_bounds__(256) void prep_w(const float* __restrict__ w0,
                                              const float* __restrict__ w1,
                                              const float* __restrict__ w2,
                                              const float* __restrict__ w3,
                                              unsigned short* __restrict__ wt) {
  __shared__ float t[32][33];
  const int op = blockIdx.z;
  const float* w = (op == 0) ? w0 : (op == 1) ? w1 : (op == 2) ? w2 : w3;
  unsigned short* o = wt + (size_t)op * DM * DM;
  const int n0 = blockIdx.x * 32, k0 = blockIdx.y * 32;
  const int tx = threadIdx.x & 31, ty = threadIdx.x >> 5;   // ty 0..7
#pragma unroll
  for (int r = 0; r < 4; ++r)
    t[r * 8 + ty][tx] = w[(size_t)(k0 + r * 8 + ty) * DM + n0 + tx];
  __syncthreads();
#pragma unroll
  for (int r = 0; r < 4; ++r)
    o[(size_t)(n0 + r * 8 + ty) * DM + k0 + tx] = f2bf(t[tx][r * 8 + ty]);
}

// ------- prep: mm = softmax(mask/128, axis=-1) * log2e, fp32 [128][128] ---------------
__global__ void prep_m(const float* __restrict__ mask, float* __restrict__ mm) {
  int row = blockIdx.x;
  int t = threadIdx.x;  // 64 threads
  float a = mask[row * 128 + t] * (1.0f / 128.0f);
  float b = mask[row * 128 + t + 64] * (1.0f / 128.0f);
  float mx = fmaxf(a, b);
  for (int s = 1; s < 64; s <<= 1) mx = fmaxf(mx, __shfl_xor(mx, s));
  float ea = __expf(a - mx), eb = __expf(b - mx);
  float sum = ea + eb;
  for (int s = 1; s < 64; s <<= 1) sum += __shfl_xor(sum, s);
  float inv = LOG2E / sum;               // prescale by log2e for attn's exp2 path
  mm[row * 128 + t] = ea * inv;
  mm[row * 128 + t + 64] = eb * inv;
}

// ---------------- conv: fp32 -> bf16, vectorized (8 elems/thread/iter) ----------------
__global__ __launch_bounds__(256) void convb(const float* __restrict__ in,
                                             unsigned short* __restrict__ out, int n8) {
  int i = blockIdx.x * 256 + threadIdx.x;
  const int stride = gridDim.x * 256;
  for (; i < n8; i += stride) {
    const float4 a = ((const float4*)in)[(size_t)i * 2];
    const float4 b = ((const float4*)in)[(size_t)i * 2 + 1];
    ushort4 lo = {f2bf(a.x), f2bf(a.y), f2bf(a.z), f2bf(a.w)};
    ushort4 hi = {f2bf(b.x), f2bf(b.y), f2bf(b.z), f2bf(b.w)};
    ((ushort4*)out)[(size_t)i * 2] = lo;
    ((ushort4*)out)[(size_t)i * 2 + 1] = hi;
  }
}

// ---------------- gemm8: [65536 x 768] bf16 A @ [768 x 768] Bt(n-major bf16) ----------
__device__ __forceinline__ void stage_tile(const unsigned short* __restrict__ src,
                                           int row0, int kcol, char* slotbase, int tid) {
  const int wid = tid >> 6, lane = tid & 63;
#pragma unroll
  for (int s = 0; s < 2; ++s) {
    const int row = s * 128 + wid * 16 + (lane >> 2);
    const int slot = lane & 3;
    gl_lds16(src + (size_t)(row0 + row) * DM + kcol + ((slot ^ ((row >> 1) & 3)) * 8),
             slotbase + s * 8192 + wid * 1024);
  }
}

template <bool OUT_BF16>
__global__ __launch_bounds__(512, 2) void gemm8(const unsigned short* __restrict__ A,
                                                const unsigned short* __restrict__ Bt,
                                                const float* __restrict__ bias,
                                                void* __restrict__ Outp) {
  __shared__ char smem[131072];   // A ring 4x16KB @0, B ring 4x16KB @65536
  const int tid = threadIdx.x, lane = tid & 63, wid = tid >> 6;
  const int cl = lane & 15, g = lane >> 4;
  const int wm = wid >> 2, wn = wid & 3;
  const int bid = blockIdx.x;
  const int xcd = bid & 7, bi = bid >> 3;        // 768 = 8 xcd * (32 m * 3 n)
  const int m0 = (xcd * 32 + bi / 3) * 256;
  const int n0 = (bi % 3) * 256;

  f32x4 acc[8][4] = {};

  auto aslot = [&](int t) { return (char*)smem + (t & 3) * 16384; };
  auto bslot = [&](int t) { return (char*)smem + 65536 + (t & 3) * 16384; };

  auto lda = [&](bf16x8* af, int t, int half) {
#pragma unroll
    for (int mi = 0; mi < 4; ++mi) {
      const int r = wm * 128 + (half * 4 + mi) * 16 + cl;
      af[mi] = *(const bf16x8*)(aslot(t) + r * 64 + ((g ^ ((r >> 1) & 3)) * 16));
    }
  };
  auto ldb = [&](bf16x8* bf, int t) {
#pragma unroll
    for (int ni = 0; ni < 4; ++ni) {
      const int r = wn * 64 + ni * 16 + cl;
      bf[ni] = *(const bf16x8*)(bslot(t) + r * 64 + ((g ^ ((r >> 1) & 3)) * 16));
    }
  };
  auto mfma16 = [&](bf16x8* af, bf16x8* bf, int half) {
    __builtin_amdgcn_s_setprio(1);
#pragma unroll
    for (int mi = 0; mi < 4; ++mi)
#pragma unroll
      for (int ni = 0; ni < 4; ++ni)
        acc[half * 4 + mi][ni] = __builtin_amdgcn_mfma_f32_16x16x32_bf16(
            af[mi], bf[ni], acc[half * 4 + mi][ni], 0, 0, 0);
    __builtin_amdgcn_s_setprio(0);
  };

  // One K-step with cross-phase prefetch. Entering: (af0, bfc) hold step-t frags.
  // ph0: stage A(t+3); drain vmcnt so B(t+1) landed (all waves) -> barrier;
  //      issue af1 reads; MFMA half0 (overlaps af1 reads).
  // ph1: stage B(t+3); issue (t+1) frag reads (slot sealed by ph0 barrier);
  //      MFMA half1 (overlaps t+1 reads); end barrier (seals slot reuse WAR).
  auto gstep = [&](int t, bool stg, int vm, bf16x8* af0, bf16x8* bfc,
                   bf16x8* af0n, bf16x8* bfn, bool last) {
    bf16x8 af1[4];
    if (stg) stage_tile(A, m0, (t + 3) * 32, aslot(t + 3), tid);
    if (vm == 6)      asm volatile("s_waitcnt vmcnt(6)" ::: "memory");
    else if (vm == 4) asm volatile("s_waitcnt vmcnt(4)" ::: "memory");
    else              asm volatile("s_waitcnt vmcnt(0)" ::: "memory");
    __builtin_amdgcn_s_barrier();
    lda(af1, t, 1);                       // ds reads overlap half0 MFMAs
    mfma16(af0, bfc, 0);
    if (stg) stage_tile(Bt, n0, (t + 3) * 32, bslot(t + 3), tid);
    if (!last) {
      lda(af0n, t + 1, 0);                // ds reads overlap half1 MFMAs
      ldb(bfn, t + 1);
    }
    mfma16(af1, bfc, 1);
    __builtin_amdgcn_s_barrier();
  };

  // prologue: tiles 0,1,2 staged; tile 0 landed; preload step-0 frags.
  stage_tile(A, m0, 0, aslot(0), tid);   stage_tile(Bt, n0, 0, bslot(0), tid);
  stage_tile(A, m0, 32, aslot(1), tid);  stage_tile(Bt, n0, 32, bslot(1), tid);
  stage_tile(A, m0, 64, aslot(2), tid);  stage_tile(Bt, n0, 64, bslot(2), tid);
  asm volatile("s_waitcnt vmcnt(8)" ::: "memory");   // A0,B0 landed
  __builtin_amdgcn_s_barrier();

  bf16x8 afA[4], bfA[4], afB[4], bfB[4];
  lda(afA, 0, 0);
  ldb(bfA, 0);

#pragma unroll 1
  for (int t = 0; t < 20; t += 2) {
    gstep(t, true, 6, afA, bfA, afB, bfB, false);
    gstep(t + 1, true, 6, afB, bfB, afA, bfA, false);
  }
  gstep(20, true, 6, afA, bfA, afB, bfB, false);
  gstep(21, false, 4, afB, bfB, afA, bfA, false);
  gstep(22, false, 0, afA, bfA, afB, bfB, false);
  gstep(23, false, 0, afB, bfB, afA, bfA, true);

  float bb[4];
#pragma unroll
  for (int ni = 0; ni < 4; ++ni) bb[ni] = bias[n0 + wn * 64 + ni * 16 + cl];
#pragma unroll
  for (int mi = 0; mi < 8; ++mi) {
    const int row = m0 + wm * 128 + mi * 16 + g * 4;
#pragma unroll
    for (int ni = 0; ni < 4; ++ni) {
      const int col = n0 + wn * 64 + ni * 16 + cl;
#pragma unroll
      for (int e = 0; e < 4; ++e) {
        float v = acc[mi][ni][e] + bb[ni];
        if constexpr (OUT_BF16)
          ((unsigned short*)Outp)[(size_t)(row + e) * DM + col] = f2bf(v);
        else
          ((float*)Outp)[(size_t)(row + e) * DM + col] = v;
      }
    }
  }
}

// ---------------- attention: 8 waves x 16 q-rows, swapped QK^T, exp2 softmax ----------
__global__ __launch_bounds__(512) void attn_k(const unsigned short* __restrict__ qp,
                                              const unsigned short* __restrict__ kp,
                                              const unsigned short* __restrict__ vp,
                                              const float* __restrict__ mm,
                                              unsigned short* __restrict__ xout) {
  __shared__ char smem[40960];
  // [0,16384):     ks [128][64] bf16, 16B-granule XOR swizzle (gi ^= row&7).
  // [16384,32768): vt [64][128] bf16, 8B granules k8 stored at k8 ^ rho(d),
  //                rho(d) = ((d&7)^((d>>3)&7))<<1 (R10-proven, conflicts -45%).
  // [32768,40960): ps [128][32] bf16 QUARTER-column of P, wave-local, 64B rows
  //                of 8 granules, gi ^= (q&3)<<1 (even XOR: b128 read pairs
  //                stay contiguous; read beat 2-way = free, write beat 4-way
  //                on b64 = acceptable). No block barrier after QK^T: ps is
  //                separate from ks and wave-local -> waves drift & overlap.
  unsigned short* vt = (unsigned short*)(smem + 16384);
  char* psb = smem + 32768;

  const int tid = threadIdx.x, lane = tid & 63, wid = tid >> 6;
  const int cl = lane & 15, g = lane >> 4;
  const int h = blockIdx.x, l = blockIdx.y;
  const size_t base = (size_t)l * 128 * DM + h * 64;
  const int q = wid * 16 + cl;                   // this lane's q-row

#pragma unroll
  for (int p = 0; p < 2; ++p) {
    const int chunk = p * 8 + wid;              // 0..15, 1KB each
    const int row = chunk * 8 + (lane >> 3);    // 128B rows
    const int gi = (lane & 7) ^ (row & 7);
    gl_lds16(kp + base + (size_t)row * DM + gi * 8, smem + chunk * 1024);
  }
  if (tid < 256) {
    const int dc = (tid & 7) * 8;
    const int kq = tid >> 3;
    int4 r0 = *(const int4*)&vp[base + (size_t)(kq * 4 + 0) * DM + dc];
    int4 r1 = *(const int4*)&vp[base + (size_t)(kq * 4 + 1) * DM + dc];
    int4 r2 = *(const int4*)&vp[base + (size_t)(kq * 4 + 2) * DM + dc];
    int4 r3 = *(const int4*)&vp[base + (size_t)(kq * 4 + 3) * DM + dc];
    const unsigned short* u0 = (const unsigned short*)&r0;
    const unsigned short* u1 = (const unsigned short*)&r1;
    const unsigned short* u2 = (const unsigned short*)&r2;
    const unsigned short* u3 = (const unsigned short*)&r3;
#pragma unroll
    for (int j = 0; j < 8; ++j) {
      // d = dc+j: d&7 = j, (d>>3)&7 = tid&7 -> rho = (j ^ (tid&7))<<1
      const int pg = kq ^ ((j ^ (tid & 7)) << 1);
      ushort4 w = {u0[j], u1[j], u2[j], u3[j]};
      *(ushort4*)&vt[(dc + j) * 128 + pg * 4] = w;
    }
  }
  bf16x8 qf[2];
#pragma unroll
  for (int ksr = 0; ksr < 2; ++ksr)
    qf[ksr] = *(const bf16x8*)&qp[base + (size_t)q * DM + ksr * 32 + g * 8];
  __syncthreads();   // ONLY block barrier: ks + vt staged & visible

  f32x4 sacc[8] = {};
  __builtin_amdgcn_s_setprio(1);
#pragma unroll
  for (int ksr = 0; ksr < 2; ++ksr) {
#pragma unroll
    for (int kf = 0; kf < 8; ++kf) {
      const int row = kf * 16 + cl;
      const int gi = (ksr * 4 + g) ^ (row & 7);
      bf16x8 kfr = *(const bf16x8*)(smem + row * 128 + gi * 16);
      sacc[kf] = __builtin_amdgcn_mfma_f32_16x16x32_bf16(kfr, qf[ksr], sacc[kf], 0, 0, 0);
    }
  }
  __builtin_amdgcn_s_setprio(0);
  // no block barrier: ps is a separate buffer and wave-local; waves proceed
  // independently from here (softmax/PV/store phases overlap across waves).

  // ---- dual softmax, exp2-folded, no max subtraction (inputs bounded)
  bf16x4 pk[8];
  {
    float4 mrow[8];
#pragma unroll
    for (int kf = 0; kf < 8; ++kf)
      mrow[kf] = *(const float4*)&mm[q * 128 + kf * 16 + g * 4];
    float sm = 0.f;
#pragma unroll
    for (int kf = 0; kf < 8; ++kf)
#pragma unroll
      for (int e = 0; e < 4; ++e) {
        float p = exp2f(sacc[kf][e] * (0.125f * LOG2E));   // = exp(s/8)
        sacc[kf][e] = p;
        sm += p;
      }
    sm += __shfl_xor(sm, 16); sm += __shfl_xor(sm, 32);
    const float inv2e = LOG2E / sm;
    float s2 = 0.f;
#pragma unroll
    for (int kf = 0; kf < 8; ++kf)
#pragma unroll
      for (int e = 0; e < 4; ++e) {
        // mrow prescaled by log2e: exp(p/sm + m) = exp2(p*inv2e + m*log2e)
        float p = exp2f(fmaf(sacc[kf][e], inv2e, ((const float*)&mrow[kf])[e]));
        sacc[kf][e] = p;
        s2 += p;
      }
    s2 += __shfl_xor(s2, 16); s2 += __shfl_xor(s2, 32);
    const float inv2 = 1.0f / s2;
#pragma unroll
    for (int kf = 0; kf < 8; ++kf)
      pk[kf] = {(__bf16)(sacc[kf][0] * inv2), (__bf16)(sacc[kf][1] * inv2),
                (__bf16)(sacc[kf][2] * inv2), (__bf16)(sacc[kf][3] * inv2)};
  }

  // ---- PV in four k-quarters through the wave-local 8KB ps buffer.
  // Quarter u: write P cols u*32..+31 (2 b64 stores) -> lgkm fence -> one
  // b128 pa read -> 4 MFMAs (fc=0..3) -> lgkm fence (WAR seal before the
  // next quarter overwrites). All wave-local; rule #18 sched_barrier after
  // each inline-asm lgkm wait.
  f32x4 xacc[4] = {};
#pragma unroll
  for (int u = 0; u < 4; ++u) {
#pragma unroll
    for (int kfr = 0; kfr < 2; ++kfr) {
      const int gi = (kfr * 4 + g) ^ ((q & 3) << 1);
      *(bf16x4*)(psb + q * 64 + gi * 8) = pk[u * 2 + kfr];
    }
    asm volatile("s_waitcnt lgkmcnt(0)" ::: "memory");
    __builtin_amdgcn_sched_barrier(0);
    __builtin_amdgcn_s_setprio(1);
    {
      const int gi = (g * 2) ^ ((q & 3) << 1);
      bf16x8 pa = *(const bf16x8*)(psb + q * 64 + gi * 8);
#pragma unroll
      for (int fc = 0; fc < 4; ++fc) {
        const int d = fc * 16 + cl;
        // rho(d) = ((d&7)^((d>>3)&7))<<1; d&7 = cl&7, (d>>3)&7 = (fc*2+(cl>>3))&7
        const int pg = (u * 8 + 2 * g) ^
                       (((cl & 7) ^ ((fc * 2 + (cl >> 3)) & 7)) << 1);
        bf16x8 bv = *(const bf16x8*)&vt[d * 128 + pg * 4];
        xacc[fc] = __builtin_amdgcn_mfma_f32_16x16x32_bf16(pa, bv, xacc[fc], 0, 0, 0);
      }
    }
    __builtin_amdgcn_s_setprio(0);
    if (u < 3) {
      asm volatile("s_waitcnt lgkmcnt(0)" ::: "memory");   // quarter reads drained
      __builtin_amdgcn_sched_barrier(0);
    }
  }

  // X-store via plain casts (compiler cvt_pk where possible)
#pragma unroll
  for (int fc = 0; fc < 4; ++fc)
#pragma unroll
    for (int e = 0; e < 4; ++e) {
      const int qr = wid * 16 + g * 4 + e;
      __bf16 b = (__bf16)xacc[fc][e];
      unsigned short u;
      __builtin_memcpy(&u, &b, 2);
      xout[base + (size_t)qr * DM + fc * 16 + cl] = u;
    }
}

extern "C" void kernel_launch(void* const* d_in, const int* in_sizes, int n_in,
                              void* d_out, int out_size, void* d_ws, size_t ws_size,
                              hipStream_t stream) {
  (void)in_sizes; (void)n_in; (void)out_size; (void)ws_size;
  const float* Q = (const float*)d_in[0];
  const float* K = (const float*)d_in[1];
  const float* V = (const float*)d_in[2];
  const float* mask = (const float*)d_in[3];
  const float* Wq = (const float*)d_in[4];
  const float* bq = (const float*)d_in[5];
  const float* Wk = (const float*)d_in[6];
  const float* bk = (const float*)d_in[7];
  const float* Wv = (const float*)d_in[8];
  const float* bv = (const float*)d_in[9];
  const float* Wo = (const float*)d_in[10];
  const float* bo = (const float*)d_in[11];

  const size_t NP = (size_t)65536 * DM;   // elements per [65536][768] bf16 buffer

  unsigned short* qp = (unsigned short*)d_out;
  unsigned short* kp = qp + NP;
  unsigned short* S1 = (unsigned short*)d_ws;
  unsigned short* S2 = S1 + NP;
  unsigned short* wt = S2 + NP;                 // [4][768*768] bf16
  float* mm = (float*)(wt + (size_t)4 * DM * DM);

  prep_w<<<dim3(24, 24, 4), 256, 0, stream>>>(Wq, Wk, Wv, Wo, wt);
  prep_m<<<dim3(128), 64, 0, stream>>>(mask, mm);

  const int n8 = (int)(NP / 8);
  dim3 g8(768);

  convb<<<dim3(2048), 256, 0, stream>>>(Q, S1, n8);
  gemm8<true><<<g8, 512, 0, stream>>>(S1, wt + 0 * (size_t)DM * DM, bq, qp);
  convb<<<dim3(2048), 256, 0, stream>>>(K, S1, n8);
  gemm8<true><<<g8, 512, 0, stream>>>(S1, wt + 1 * (size_t)DM * DM, bk, kp);
  convb<<<dim3(2048), 256, 0, stream>>>(V, S2, n8);
  gemm8<true><<<g8, 512, 0, stream>>>(S2, wt + 2 * (size_t)DM * DM, bv, S1);

  attn_k<<<dim3(12, 512), 512, 0, stream>>>(qp, kp, S1, mm, S1);

  gemm8<false><<<g8, 512, 0, stream>>>(S1, wt + 3 * (size_t)DM * DM, bo, (float*)d_out);
}

// Round 13
// 661.214 us; speedup vs baseline: 1.0120x; 1.0120x over previous
//
#include <hip/hip_runtime.h>

// MultiHeadedAttention: out = ((softmax(softmax(QK^T/8)+softmax(mask/128)))V) @ Wo
// Q,K,V (128,512,768) fp32 -> flat [65536][768]. Attention slice (l,h) = rows
// l*128..+127, cols h*64..+63 of the flat projection buffers.
// R12 post-mortem: quarter-ps raised occupancy 51->67% but attn 120->122us ->
// occupancy is NOT attn's binding constraint (fence count is). Per the R11
// pre-commitment this round LOCKS the best-measured config per component:
//   attn  = R11: half-ps 49KB, post-QK^T block barrier DELETED (-3us, the
//           only attn win), rho-vt swizzle (conflicts -45%), exp2-folded dual
//           softmax, ps column-halves with wave-local lgkm fences.
//   gemm8 = R1 256^2 cross-phase schedule (~97us; 5 structural alternatives
//           — fusion, paired steps, 8-phase, 2-slot dbuf, 128^2 — all lost).
//   convb = HBM-roofline fp32->bf16 staging (~48us each).
// Remaining structural constraints (out of single-variable reach): attn's
// per-wave serial chain (stage -> QK^T -> 64 exp2 -> P round-trip -> PV) only
// covered by 3 blocks/CU TLP — needs cross-tile fusion (R2: -74%) or asm wave
// specialization; gemm's 36% MfmaUtil = 2-barrier-structure ceiling (8-phase
// barrier overhead exceeds its gain at K=768).

typedef __attribute__((ext_vector_type(8))) __bf16 bf16x8;
typedef __attribute__((ext_vector_type(4))) __bf16 bf16x4;
typedef __attribute__((ext_vector_type(4))) float f32x4;

#define DM 768
#define LOG2E 1.44269504f

__device__ __forceinline__ unsigned short f2bf(float x) {
  unsigned u = __float_as_uint(x);
  u += 0x7FFFu + ((u >> 16) & 1u);   // RNE
  return (unsigned short)(u >> 16);
}

__device__ __forceinline__ void gl_lds16(const void* g, void* l) {
  __builtin_amdgcn_global_load_lds(
      (const __attribute__((address_space(1))) unsigned int*)g,
      (__attribute__((address_space(3))) unsigned int*)l, 16, 0, 0);
}

// ---------------- prep: transpose+convert 4 weights to bf16 [op][n][k] ----------------
__global__ __launch_bounds__(256) void prep_w(const float* __restrict__ w0,
                                              const float* __restrict__ w1,
                                              const float* __restrict__ w2,
                                              const float* __restrict__ w3,
                                              unsigned short* __restrict__ wt) {
  __shared__ float t[32][33];
  const int op = blockIdx.z;
  const float* w = (op == 0) ? w0 : (op == 1) ? w1 : (op == 2) ? w2 : w3;
  unsigned short* o = wt + (size_t)op * DM * DM;
  const int n0 = blockIdx.x * 32, k0 = blockIdx.y * 32;
  const int tx = threadIdx.x & 31, ty = threadIdx.x >> 5;   // ty 0..7
#pragma unroll
  for (int r = 0; r < 4; ++r)
    t[r * 8 + ty][tx] = w[(size_t)(k0 + r * 8 + ty) * DM + n0 + tx];
  __syncthreads();
#pragma unroll
  for (int r = 0; r < 4; ++r)
    o[(size_t)(n0 + r * 8 + ty) * DM + k0 + tx] = f2bf(t[tx][r * 8 + ty]);
}

// ------- prep: mm = softmax(mask/128, axis=-1) * log2e, fp32 [128][128] ---------------
__global__ void prep_m(const float* __restrict__ mask, float* __restrict__ mm) {
  int row = blockIdx.x;
  int t = threadIdx.x;  // 64 threads
  float a = mask[row * 128 + t] * (1.0f / 128.0f);
  float b = mask[row * 128 + t + 64] * (1.0f / 128.0f);
  float mx = fmaxf(a, b);
  for (int s = 1; s < 64; s <<= 1) mx = fmaxf(mx, __shfl_xor(mx, s));
  float ea = __expf(a - mx), eb = __expf(b - mx);
  float sum = ea + eb;
  for (int s = 1; s < 64; s <<= 1) sum += __shfl_xor(sum, s);
  float inv = LOG2E / sum;               // prescale by log2e for attn's exp2 path
  mm[row * 128 + t] = ea * inv;
  mm[row * 128 + t + 64] = eb * inv;
}

// ---------------- conv: fp32 -> bf16, vectorized (8 elems/thread/iter) ----------------
__global__ __launch_bounds__(256) void convb(const float* __restrict__ in,
                                             unsigned short* __restrict__ out, int n8) {
  int i = blockIdx.x * 256 + threadIdx.x;
  const int stride = gridDim.x * 256;
  for (; i < n8; i += stride) {
    const float4 a = ((const float4*)in)[(size_t)i * 2];
    const float4 b = ((const float4*)in)[(size_t)i * 2 + 1];
    ushort4 lo = {f2bf(a.x), f2bf(a.y), f2bf(a.z), f2bf(a.w)};
    ushort4 hi = {f2bf(b.x), f2bf(b.y), f2bf(b.z), f2bf(b.w)};
    ((ushort4*)out)[(size_t)i * 2] = lo;
    ((ushort4*)out)[(size_t)i * 2 + 1] = hi;
  }
}

// ---------------- gemm8: [65536 x 768] bf16 A @ [768 x 768] Bt(n-major bf16) ----------
__device__ __forceinline__ void stage_tile(const unsigned short* __restrict__ src,
                                           int row0, int kcol, char* slotbase, int tid) {
  const int wid = tid >> 6, lane = tid & 63;
#pragma unroll
  for (int s = 0; s < 2; ++s) {
    const int row = s * 128 + wid * 16 + (lane >> 2);
    const int slot = lane & 3;
    gl_lds16(src + (size_t)(row0 + row) * DM + kcol + ((slot ^ ((row >> 1) & 3)) * 8),
             slotbase + s * 8192 + wid * 1024);
  }
}

template <bool OUT_BF16>
__global__ __launch_bounds__(512, 2) void gemm8(const unsigned short* __restrict__ A,
                                                const unsigned short* __restrict__ Bt,
                                                const float* __restrict__ bias,
                                                void* __restrict__ Outp) {
  __shared__ char smem[131072];   // A ring 4x16KB @0, B ring 4x16KB @65536
  const int tid = threadIdx.x, lane = tid & 63, wid = tid >> 6;
  const int cl = lane & 15, g = lane >> 4;
  const int wm = wid >> 2, wn = wid & 3;
  const int bid = blockIdx.x;
  const int xcd = bid & 7, bi = bid >> 3;        // 768 = 8 xcd * (32 m * 3 n)
  const int m0 = (xcd * 32 + bi / 3) * 256;
  const int n0 = (bi % 3) * 256;

  f32x4 acc[8][4] = {};

  auto aslot = [&](int t) { return (char*)smem + (t & 3) * 16384; };
  auto bslot = [&](int t) { return (char*)smem + 65536 + (t & 3) * 16384; };

  auto lda = [&](bf16x8* af, int t, int half) {
#pragma unroll
    for (int mi = 0; mi < 4; ++mi) {
      const int r = wm * 128 + (half * 4 + mi) * 16 + cl;
      af[mi] = *(const bf16x8*)(aslot(t) + r * 64 + ((g ^ ((r >> 1) & 3)) * 16));
    }
  };
  auto ldb = [&](bf16x8* bf, int t) {
#pragma unroll
    for (int ni = 0; ni < 4; ++ni) {
      const int r = wn * 64 + ni * 16 + cl;
      bf[ni] = *(const bf16x8*)(bslot(t) + r * 64 + ((g ^ ((r >> 1) & 3)) * 16));
    }
  };
  auto mfma16 = [&](bf16x8* af, bf16x8* bf, int half) {
    __builtin_amdgcn_s_setprio(1);
#pragma unroll
    for (int mi = 0; mi < 4; ++mi)
#pragma unroll
      for (int ni = 0; ni < 4; ++ni)
        acc[half * 4 + mi][ni] = __builtin_amdgcn_mfma_f32_16x16x32_bf16(
            af[mi], bf[ni], acc[half * 4 + mi][ni], 0, 0, 0);
    __builtin_amdgcn_s_setprio(0);
  };

  // One K-step with cross-phase prefetch. Entering: (af0, bfc) hold step-t frags.
  // ph0: stage A(t+3); drain vmcnt so B(t+1) landed (all waves) -> barrier;
  //      issue af1 reads; MFMA half0 (overlaps af1 reads).
  // ph1: stage B(t+3); issue (t+1) frag reads (slot sealed by ph0 barrier);
  //      MFMA half1 (overlaps t+1 reads); end barrier (seals slot reuse WAR).
  auto gstep = [&](int t, bool stg, int vm, bf16x8* af0, bf16x8* bfc,
                   bf16x8* af0n, bf16x8* bfn, bool last) {
    bf16x8 af1[4];
    if (stg) stage_tile(A, m0, (t + 3) * 32, aslot(t + 3), tid);
    if (vm == 6)      asm volatile("s_waitcnt vmcnt(6)" ::: "memory");
    else if (vm == 4) asm volatile("s_waitcnt vmcnt(4)" ::: "memory");
    else              asm volatile("s_waitcnt vmcnt(0)" ::: "memory");
    __builtin_amdgcn_s_barrier();
    lda(af1, t, 1);                       // ds reads overlap half0 MFMAs
    mfma16(af0, bfc, 0);
    if (stg) stage_tile(Bt, n0, (t + 3) * 32, bslot(t + 3), tid);
    if (!last) {
      lda(af0n, t + 1, 0);                // ds reads overlap half1 MFMAs
      ldb(bfn, t + 1);
    }
    mfma16(af1, bfc, 1);
    __builtin_amdgcn_s_barrier();
  };

  // prologue: tiles 0,1,2 staged; tile 0 landed; preload step-0 frags.
  stage_tile(A, m0, 0, aslot(0), tid);   stage_tile(Bt, n0, 0, bslot(0), tid);
  stage_tile(A, m0, 32, aslot(1), tid);  stage_tile(Bt, n0, 32, bslot(1), tid);
  stage_tile(A, m0, 64, aslot(2), tid);  stage_tile(Bt, n0, 64, bslot(2), tid);
  asm volatile("s_waitcnt vmcnt(8)" ::: "memory");   // A0,B0 landed
  __builtin_amdgcn_s_barrier();

  bf16x8 afA[4], bfA[4], afB[4], bfB[4];
  lda(afA, 0, 0);
  ldb(bfA, 0);

#pragma unroll 1
  for (int t = 0; t < 20; t += 2) {
    gstep(t, true, 6, afA, bfA, afB, bfB, false);
    gstep(t + 1, true, 6, afB, bfB, afA, bfA, false);
  }
  gstep(20, true, 6, afA, bfA, afB, bfB, false);
  gstep(21, false, 4, afB, bfB, afA, bfA, false);
  gstep(22, false, 0, afA, bfA, afB, bfB, false);
  gstep(23, false, 0, afB, bfB, afA, bfA, true);

  float bb[4];
#pragma unroll
  for (int ni = 0; ni < 4; ++ni) bb[ni] = bias[n0 + wn * 64 + ni * 16 + cl];
#pragma unroll
  for (int mi = 0; mi < 8; ++mi) {
    const int row = m0 + wm * 128 + mi * 16 + g * 4;
#pragma unroll
    for (int ni = 0; ni < 4; ++ni) {
      const int col = n0 + wn * 64 + ni * 16 + cl;
#pragma unroll
      for (int e = 0; e < 4; ++e) {
        float v = acc[mi][ni][e] + bb[ni];
        if constexpr (OUT_BF16)
          ((unsigned short*)Outp)[(size_t)(row + e) * DM + col] = f2bf(v);
        else
          ((float*)Outp)[(size_t)(row + e) * DM + col] = v;
      }
    }
  }
}

// ---------------- attention: 8 waves x 16 q-rows, swapped QK^T, exp2 softmax ----------
__global__ __launch_bounds__(512) void attn_k(const unsigned short* __restrict__ qp,
                                              const unsigned short* __restrict__ kp,
                                              const unsigned short* __restrict__ vp,
                                              const float* __restrict__ mm,
                                              unsigned short* __restrict__ xout) {
  __shared__ char smem[49152];
  // [0,16384):     ks [128][64] bf16, 16B-granule XOR swizzle (gi ^= row&7).
  // [16384,32768): vt [64][128] bf16, 8B granules k8 stored at k8 ^ rho(d),
  //                rho(d) = ((d&7)^((d>>3)&7))<<1 (R10-proven, conflicts -45%).
  // [32768,49152): ps [128][64] bf16 COLUMN-HALF of P, wave-local, 8B granules
  //                gi ^= (q&3)<<2. Separate from ks -> no cross-wave WAR ->
  //                post-QK^T block barrier deleted (R11-proven, -3us); all
  //                post-staging phases are wave-independent (waves drift).
  unsigned short* vt = (unsigned short*)(smem + 16384);
  char* psb = smem + 32768;

  const int tid = threadIdx.x, lane = tid & 63, wid = tid >> 6;
  const int cl = lane & 15, g = lane >> 4;
  const int h = blockIdx.x, l = blockIdx.y;
  const size_t base = (size_t)l * 128 * DM + h * 64;
  const int q = wid * 16 + cl;                   // this lane's q-row

#pragma unroll
  for (int p = 0; p < 2; ++p) {
    const int chunk = p * 8 + wid;              // 0..15, 1KB each
    const int row = chunk * 8 + (lane >> 3);    // 128B rows
    const int gi = (lane & 7) ^ (row & 7);
    gl_lds16(kp + base + (size_t)row * DM + gi * 8, smem + chunk * 1024);
  }
  if (tid < 256) {
    const int dc = (tid & 7) * 8;
    const int kq = tid >> 3;
    int4 r0 = *(const int4*)&vp[base + (size_t)(kq * 4 + 0) * DM + dc];
    int4 r1 = *(const int4*)&vp[base + (size_t)(kq * 4 + 1) * DM + dc];
    int4 r2 = *(const int4*)&vp[base + (size_t)(kq * 4 + 2) * DM + dc];
    int4 r3 = *(const int4*)&vp[base + (size_t)(kq * 4 + 3) * DM + dc];
    const unsigned short* u0 = (const unsigned short*)&r0;
    const unsigned short* u1 = (const unsigned short*)&r1;
    const unsigned short* u2 = (const unsigned short*)&r2;
    const unsigned short* u3 = (const unsigned short*)&r3;
#pragma unroll
    for (int j = 0; j < 8; ++j) {
      // d = dc+j: d&7 = j, (d>>3)&7 = tid&7 -> rho = (j ^ (tid&7))<<1
      const int pg = kq ^ ((j ^ (tid & 7)) << 1);
      ushort4 w = {u0[j], u1[j], u2[j], u3[j]};
      *(ushort4*)&vt[(dc + j) * 128 + pg * 4] = w;
    }
  }
  bf16x8 qf[2];
#pragma unroll
  for (int ksr = 0; ksr < 2; ++ksr)
    qf[ksr] = *(const bf16x8*)&qp[base + (size_t)q * DM + ksr * 32 + g * 8];
  __syncthreads();   // ONLY block barrier: ks + vt staged & visible

  f32x4 sacc[8] = {};
  __builtin_amdgcn_s_setprio(1);
#pragma unroll
  for (int ksr = 0; ksr < 2; ++ksr) {
#pragma unroll
    for (int kf = 0; kf < 8; ++kf) {
      const int row = kf * 16 + cl;
      const int gi = (ksr * 4 + g) ^ (row & 7);
      bf16x8 kfr = *(const bf16x8*)(smem + row * 128 + gi * 16);
      sacc[kf] = __builtin_amdgcn_mfma_f32_16x16x32_bf16(kfr, qf[ksr], sacc[kf], 0, 0, 0);
    }
  }
  __builtin_amdgcn_s_setprio(0);
  // no block barrier: ps is a separate buffer and wave-local; waves proceed
  // independently from here (softmax/PV/store phases overlap across waves).

  // ---- dual softmax, exp2-folded, no max subtraction (inputs bounded)
  bf16x4 pk[8];
  {
    float4 mrow[8];
#pragma unroll
    for (int kf = 0; kf < 8; ++kf)
      mrow[kf] = *(const float4*)&mm[q * 128 + kf * 16 + g * 4];
    float sm = 0.f;
#pragma unroll
    for (int kf = 0; kf < 8; ++kf)
#pragma unroll
      for (int e = 0; e < 4; ++e) {
        float p = exp2f(sacc[kf][e] * (0.125f * LOG2E));   // = exp(s/8)
        sacc[kf][e] = p;
        sm += p;
      }
    sm += __shfl_xor(sm, 16); sm += __shfl_xor(sm, 32);
    const float inv2e = LOG2E / sm;
    float s2 = 0.f;
#pragma unroll
    for (int kf = 0; kf < 8; ++kf)
#pragma unroll
      for (int e = 0; e < 4; ++e) {
        // mrow prescaled by log2e: exp(p/sm + m) = exp2(p*inv2e + m*log2e)
        float p = exp2f(fmaf(sacc[kf][e], inv2e, ((const float*)&mrow[kf])[e]));
        sacc[kf][e] = p;
        s2 += p;
      }
    s2 += __shfl_xor(s2, 16); s2 += __shfl_xor(s2, 32);
    const float inv2 = 1.0f / s2;
#pragma unroll
    for (int kf = 0; kf < 8; ++kf)
      pk[kf] = {(__bf16)(sacc[kf][0] * inv2), (__bf16)(sacc[kf][1] * inv2),
                (__bf16)(sacc[kf][2] * inv2), (__bf16)(sacc[kf][3] * inv2)};
  }

  // ---- PV in two column-halves through the wave-local ps buffer (own rows;
  // lgkm fences only; rule #18 sched_barrier after each).
  f32x4 xacc[4] = {};
#pragma unroll
  for (int half = 0; half < 2; ++half) {
#pragma unroll
    for (int kf = 0; kf < 4; ++kf) {
      const int gi = (kf * 4 + g) ^ ((q & 3) << 2);
      *(bf16x4*)(psb + q * 128 + gi * 8) = pk[half * 4 + kf];
    }
    asm volatile("s_waitcnt lgkmcnt(0)" ::: "memory");
    __builtin_amdgcn_sched_barrier(0);
    __builtin_amdgcn_s_setprio(1);
#pragma unroll
    for (int k2 = 0; k2 < 2; ++k2) {
      const int ks2 = half * 2 + k2;
      const int gi = (k2 * 8 + g * 2) ^ ((q & 3) << 2);
      bf16x8 pa = *(const bf16x8*)(psb + q * 128 + gi * 8);
#pragma unroll
      for (int fc = 0; fc < 4; ++fc) {
        const int d = fc * 16 + cl;
        // rho(d) = ((d&7)^((d>>3)&7))<<1; d&7 = cl&7, (d>>3)&7 = (fc*2+(cl>>3))&7
        const int pg = (ks2 * 8 + 2 * g) ^
                       (((cl & 7) ^ ((fc * 2 + (cl >> 3)) & 7)) << 1);
        bf16x8 bv = *(const bf16x8*)&vt[d * 128 + pg * 4];
        xacc[fc] = __builtin_amdgcn_mfma_f32_16x16x32_bf16(pa, bv, xacc[fc], 0, 0, 0);
      }
    }
    __builtin_amdgcn_s_setprio(0);
    if (half == 0) {
      asm volatile("s_waitcnt lgkmcnt(0)" ::: "memory");   // half-0 reads drained
      __builtin_amdgcn_sched_barrier(0);
    }
  }

  // X-store via plain casts (compiler cvt_pk where possible)
#pragma unroll
  for (int fc = 0; fc < 4; ++fc)
#pragma unroll
    for (int e = 0; e < 4; ++e) {
      const int qr = wid * 16 + g * 4 + e;
      __bf16 b = (__bf16)xacc[fc][e];
      unsigned short u;
      __builtin_memcpy(&u, &b, 2);
      xout[base + (size_t)qr * DM + fc * 16 + cl] = u;
    }
}

extern "C" void kernel_launch(void* const* d_in, const int* in_sizes, int n_in,
                              void* d_out, int out_size, void* d_ws, size_t ws_size,
                              hipStream_t stream) {
  (void)in_sizes; (void)n_in; (void)out_size; (void)ws_size;
  const float* Q = (const float*)d_in[0];
  const float* K = (const float*)d_in[1];
  const float* V = (const float*)d_in[2];
  const float* mask = (const float*)d_in[3];
  const float* Wq = (const float*)d_in[4];
  const float* bq = (const float*)d_in[5];
  const float* Wk = (const float*)d_in[6];
  const float* bk = (const float*)d_in[7];
  const float* Wv = (const float*)d_in[8];
  const float* bv = (const float*)d_in[9];
  const float* Wo = (const float*)d_in[10];
  const float* bo = (const float*)d_in[11];

  const size_t NP = (size_t)65536 * DM;   // elements per [65536][768] bf16 buffer

  unsigned short* qp = (unsigned short*)d_out;
  unsigned short* kp = qp + NP;
  unsigned short* S1 = (unsigned short*)d_ws;
  unsigned short* S2 = S1 + NP;
  unsigned short* wt = S2 + NP;                 // [4][768*768] bf16
  float* mm = (float*)(wt + (size_t)4 * DM * DM);

  prep_w<<<dim3(24, 24, 4), 256, 0, stream>>>(Wq, Wk, Wv, Wo, wt);
  prep_m<<<dim3(128), 64, 0, stream>>>(mask, mm);

  const int n8 = (int)(NP / 8);
  dim3 g8(768);

  convb<<<dim3(2048), 256, 0, stream>>>(Q, S1, n8);
  gemm8<true><<<g8, 512, 0, stream>>>(S1, wt + 0 * (size_t)DM * DM, bq, qp);
  convb<<<dim3(2048), 256, 0, stream>>>(K, S1, n8);
  gemm8<true><<<g8, 512, 0, stream>>>(S1, wt + 1 * (size_t)DM * DM, bk, kp);
  convb<<<dim3(2048), 256, 0, stream>>>(V, S2, n8);
  gemm8<true><<<g8, 512, 0, stream>>>(S2, wt + 2 * (size_t)DM * DM, bv, S1);

  attn_k<<<dim3(12, 512), 512, 0, stream>>>(qp, kp, S1, mm, S1);

  gemm8<false><<<g8, 512, 0, stream>>>(S1, wt + 3 * (size_t)DM * DM, bo, (float*)d_out);
}